// Round 4
// baseline (221.217 us; speedup 1.0000x reference)
//
#include <hip/hip_runtime.h>
#include <math.h>

#define HDIM 768
#define BDIM 256
#define INDIM 64
#define NLAYERS 4
#define PDIM 8
#define KSPLIT 8      // trop k-split: 8 slots x 96k (critical path invariant vs 24; 3x less partial traffic)
#define KLEN 96
#define CHK 16
#define TR 128
#define TC 64
#define NTROPBLK 192  // 24 spatial x 8 slots
#define NCGBLK 192    // 4 m x 24 n x 2 mats
#define NBLK (NTROPBLK + NCGBLK)   // 384
#define PSTRIDE 196864  // NBH + 256 floats: de-alias 768KB stride in L2 sets

typedef short bf16x8 __attribute__((ext_vector_type(8)));
typedef float f32x4 __attribute__((ext_vector_type(4)));

__device__ __forceinline__ float sigmoidf_(float x) { return 1.f / (1.f + expf(-x)); }
__device__ __forceinline__ float geluf_(float x) { return 0.5f * x * (1.f + erff(x * 0.70710678118654752f)); }
__device__ __forceinline__ unsigned short f2bf(float f) {
    unsigned int u = __float_as_uint(f);
    u += 0x7FFFu + ((u >> 16) & 1u);          // RNE
    return (unsigned short)(u >> 16);
}

// async global->LDS, 16B/lane
__device__ __forceinline__ void gload_lds16(const float* g, float* l) {
    __builtin_amdgcn_global_load_lds((const __attribute__((address_space(1))) void*)g,
                                     (__attribute__((address_space(3))) void*)l, 16, 0, 0);
}

// ---------------------------------------------------------------------------
// Merged prep + input: grid (12,12,14).
//  z<4 : trop_w[l=z] [o][i] fp32 -> twT[l] [i][o] fp32
//  z in [4,12): zz=z-4, l=zz>>1, mat=zz&1: cls/gate [k][o] fp32 -> wB[o][k] bf16
//  z in [12,14): input GEMM h = x@w_in + b_in, LN(layer0) -> hnT/hnB, 1 row/blk
// ---------------------------------------------------------------------------
__global__ __launch_bounds__(256) void prep_k(const float* __restrict__ trop_w,
                                              const float* __restrict__ cls_w,
                                              const float* __restrict__ gate_w,
                                              float* __restrict__ twT,
                                              unsigned short* __restrict__ wB,
                                              const float* __restrict__ x,
                                              const float* __restrict__ w_in,
                                              const float* __restrict__ b_in,
                                              const float* __restrict__ lng,
                                              const float* __restrict__ lnb,
                                              float* __restrict__ h,
                                              float* __restrict__ hnT,
                                              unsigned short* __restrict__ hnB)
{
    __shared__ float tile[64][65];
    const int z = blockIdx.z;
    const int a0 = blockIdx.x * 64;
    const int b0 = blockIdx.y * 64;
    const int c = threadIdx.x & 63;
    const int r4 = threadIdx.x >> 6;

    if (z < NLAYERS) {
        const float* s = trop_w + (size_t)z * HDIM * HDIM;
        float* d = twT + (size_t)z * HDIM * HDIM;
#pragma unroll
        for (int it = 0; it < 16; ++it) {
            const int r = it * 4 + r4;
            tile[r][c] = s[(size_t)(a0 + r) * HDIM + b0 + c];
        }
        __syncthreads();
#pragma unroll
        for (int it = 0; it < 16; ++it) {
            const int r = it * 4 + r4;
            d[(size_t)(b0 + r) * HDIM + a0 + c] = tile[c][r];
        }
    } else if (z < 12) {
        const int zz = z - NLAYERS;
        const int l = zz >> 1, mat = zz & 1;
        const float* s = (mat ? gate_w : cls_w) + (size_t)l * HDIM * HDIM;
        unsigned short* d = wB + (size_t)zz * HDIM * HDIM;
#pragma unroll
        for (int it = 0; it < 16; ++it) {
            const int r = it * 4 + r4;                          // k
            tile[r][c] = s[(size_t)(b0 + r) * HDIM + a0 + c];   // c = o
        }
        __syncthreads();
#pragma unroll
        for (int it = 0; it < 16; ++it) {
            const int r = it * 4 + r4;                          // o
            d[(size_t)(a0 + r) * HDIM + b0 + c] = f2bf(tile[c][r]);
        }
    } else {
        // ---- input GEMM + LN(layer 0), one batch row per block ----
        const int idx = (z - 12) * 144 + blockIdx.y * 12 + blockIdx.x;
        if (idx >= BDIM) return;
        const int b = idx;
        const int t = threadIdx.x;
        float* xs = &tile[0][0];    // 64 floats
        float* rb = &tile[1][0];    // 8 floats (4 waves x s,q)
        if (t < INDIM) xs[t] = x[b * INDIM + t];
        __syncthreads();

        float acc0 = b_in[t], acc1 = b_in[t + 256], acc2 = b_in[t + 512];
#pragma unroll 8
        for (int i = 0; i < INDIM; ++i) {
            const float xv = xs[i];
            acc0 = fmaf(xv, w_in[(size_t)i * HDIM + t], acc0);
            acc1 = fmaf(xv, w_in[(size_t)i * HDIM + t + 256], acc1);
            acc2 = fmaf(xv, w_in[(size_t)i * HDIM + t + 512], acc2);
        }
        h[(size_t)b * HDIM + t] = acc0;
        h[(size_t)b * HDIM + t + 256] = acc1;
        h[(size_t)b * HDIM + t + 512] = acc2;

        float s = acc0 + acc1 + acc2;
        float q = acc0 * acc0 + acc1 * acc1 + acc2 * acc2;
#pragma unroll
        for (int off = 32; off > 0; off >>= 1) { s += __shfl_down(s, off); q += __shfl_down(q, off); }
        const int wid = t >> 6, lane = t & 63;
        if (lane == 0) { rb[wid] = s; rb[4 + wid] = q; }
        __syncthreads();
        s = rb[0] + rb[1] + rb[2] + rb[3];
        q = rb[4] + rb[5] + rb[6] + rb[7];
        const float mu = s * (1.f / HDIM);
        const float var = q * (1.f / HDIM) - mu * mu;
        const float rsig = rsqrtf(var + 1e-5f);

#pragma unroll
        for (int qq = 0; qq < 3; ++qq) {
            const int o = t + qq * 256;
            const float av = (qq == 0) ? acc0 : (qq == 1) ? acc1 : acc2;
            const float v = (av - mu) * rsig * lng[o] + lnb[o];
            hnT[(size_t)o * BDIM + b] = v;
            hnB[(size_t)b * HDIM + o] = f2bf(v);
        }
    }
}

// ---------------------------------------------------------------------------
// Kernel 1 (per layer, ONE dispatch): block-partitioned fusion.
//   blocks [0,192):   TROPICAL fp32 tiles, KLEN=96 (exact; CHK=16 dbuf x6)
//   blocks [192,384): CLS+GATE bf16 MFMA tiles (one mat per block)
// KSPLIT=8: per-block trop work 3x vs KSPLIT=24 but worst-CU cycle count is
// identical (1 block x 12288 cyc vs 3 x 4096); p_trop traffic shrinks 3x.
// ---------------------------------------------------------------------------
__global__ __launch_bounds__(256, 2) void layer_mm_k(
    const float* __restrict__ hnT,        // fp32 [k][b]
    const float* __restrict__ twT,        // fp32 trop_w^T [k][o] (this layer)
    const unsigned short* __restrict__ hnB,  // bf16 [b][k]
    const unsigned short* __restrict__ wB,   // bf16 [mat][o][k] (this layer)
    float* __restrict__ p_trop, float* __restrict__ p_cls, float* __restrict__ p_gate)
{
    __shared__ float hn_s[2][CHK][TR];
    __shared__ float wt_s[2][CHK][TC];

    const int bx = blockIdx.x;
    const int tid = threadIdx.x;
    const int wave = tid >> 6, lane = tid & 63;

    if (bx < NTROPBLK) {
        // ---------------- tropical (fp32, exact) ----------------
        const int sp = bx % 24;
        const int slot = bx / 24;              // 0..7
        const int col0 = (sp % 12) * TC;
        const int row0 = (sp / 12) * TR;
        const int k0 = slot * KLEN;

        const int tx = tid & 15, ty = tid >> 4;
        const int r0 = ty * 8, c0 = tx * 4;

        const int hk = lane >> 5;
        const int hcol = (lane & 31) * 4;
        const int wr = lane >> 4;
        const int wcol = (lane & 15) * 4;

        float t_acc[8][4];
#pragma unroll
        for (int i = 0; i < 8; ++i)
#pragma unroll
            for (int j = 0; j < 4; ++j) t_acc[i][j] = -1e30f;

        #define STAGE_T(buf, kb)                                                                   \
        {                                                                                          \
            gload_lds16(hnT + (size_t)((kb) + 4 * wave + hk) * BDIM + row0 + hcol,                 \
                        &hn_s[buf][4 * wave][0]);                                                  \
            gload_lds16(hnT + (size_t)((kb) + 4 * wave + 2 + hk) * BDIM + row0 + hcol,             \
                        &hn_s[buf][4 * wave + 2][0]);                                              \
            gload_lds16(twT + (size_t)((kb) + 4 * wave + wr) * HDIM + col0 + wcol,                 \
                        &wt_s[buf][4 * wave][0]);                                                  \
        }

        STAGE_T(0, k0);
        __builtin_amdgcn_s_waitcnt(0);
        __syncthreads();

        for (int c = 0; c < KLEN / CHK; ++c) {
            const int buf = c & 1;
            if (c + 1 < KLEN / CHK) STAGE_T(1 - buf, k0 + (c + 1) * CHK);
#pragma unroll
            for (int k = 0; k < CHK; ++k) {
                const float4 h0 = *(const float4*)&hn_s[buf][k][r0];
                const float4 h1 = *(const float4*)&hn_s[buf][k][r0 + 4];
                const float4 wt = *(const float4*)&wt_s[buf][k][c0];
                const float hf[8] = {h0.x, h0.y, h0.z, h0.w, h1.x, h1.y, h1.z, h1.w};
                const float wtf[4] = {wt.x, wt.y, wt.z, wt.w};
#pragma unroll
                for (int i = 0; i < 8; ++i)
#pragma unroll
                    for (int j = 0; j < 4; ++j)
                        t_acc[i][j] = fmaxf(t_acc[i][j], hf[i] + wtf[j]);
            }
            __builtin_amdgcn_s_waitcnt(0);
            __syncthreads();
        }
        #undef STAGE_T

        const size_t base = (size_t)slot * PSTRIDE;
#pragma unroll
        for (int i = 0; i < 8; ++i) {
            const size_t off = base + (size_t)(row0 + r0 + i) * HDIM + col0 + c0;
            *(float4*)(p_trop + off) = make_float4(t_acc[i][0], t_acc[i][1], t_acc[i][2], t_acc[i][3]);
        }
    } else {
        // ---------------- cls+gate (bf16 MFMA, full K, 1 mat/block) --------
        // Layouts (HW-verified): A[m=lane&15][k=q*8+j], B[k][n=lane&15],
        // D[m=q*4+r][n=lane&15].
        const int cb = bx - NTROPBLK;          // 0..191
        const int mat = cb & 1;
        const int nt = (cb >> 1) % 24;         // 24 n-tiles of 32
        const int mt = cb / 48;                // 4 m-tiles of 64
        const int m0 = mt * 64 + wave * 16;
        const int n0 = nt * 32;
        const int lm = lane & 15, q = lane >> 4;

        const unsigned short* wmat = wB + (size_t)mat * HDIM * HDIM;
        float* pout = mat ? p_gate : p_cls;

        f32x4 acc[2];
        acc[0] = (f32x4){0.f, 0.f, 0.f, 0.f};
        acc[1] = (f32x4){0.f, 0.f, 0.f, 0.f};

        const unsigned short* aptr = hnB + (size_t)(m0 + lm) * HDIM + q * 8;
        const unsigned short* b0 = wmat + (size_t)(n0 + lm) * HDIM + q * 8;
        const unsigned short* b1 = b0 + (size_t)16 * HDIM;

#pragma unroll 4
        for (int k0 = 0; k0 < HDIM; k0 += 32) {
            const bf16x8 a  = *(const bf16x8*)(aptr + k0);
            const bf16x8 v0 = *(const bf16x8*)(b0 + k0);
            const bf16x8 v1 = *(const bf16x8*)(b1 + k0);
            acc[0] = __builtin_amdgcn_mfma_f32_16x16x32_bf16(a, v0, acc[0], 0, 0, 0);
            acc[1] = __builtin_amdgcn_mfma_f32_16x16x32_bf16(a, v1, acc[1], 0, 0, 0);
        }

#pragma unroll
        for (int nn = 0; nn < 2; ++nn)
#pragma unroll
            for (int r = 0; r < 4; ++r)
                pout[(size_t)(m0 + q * 4 + r) * HDIM + n0 + nn * 16 + lm] = acc[nn][r];
    }
}

// ---------------------------------------------------------------------------
// Kernel 2 (per layer): reduce trop partials, LF activation, gelu, gate,
// residual, then LN -> hnT/hnB for next layer (or final LN + head -> out).
// ---------------------------------------------------------------------------
__global__ __launch_bounds__(768) void combine_k(
    const float* __restrict__ p_trop, const float* __restrict__ p_cls, const float* __restrict__ p_gate,
    const float* __restrict__ trop_b,
    const float* __restrict__ amax, const float* __restrict__ bmax,
    const float* __restrict__ amin, const float* __restrict__ bmin,
    const float* __restrict__ alpha,
    const float* __restrict__ gate_b, const float* __restrict__ cls_b,
    float* __restrict__ h,
    const float* __restrict__ lng, const float* __restrict__ lnb,
    float* __restrict__ hnT, unsigned short* __restrict__ hnB,
    const float* __restrict__ head_w, const float* __restrict__ head_b,
    float* __restrict__ out, const int is_last)
{
    const int b = blockIdx.x;
    const int o = threadIdx.x;         // 0..767
    __shared__ float rbuf[12], qbuf[12];

    const size_t base = (size_t)b * HDIM + o;
    float tm = -1e30f;
#pragma unroll
    for (int k = 0; k < KSPLIT; ++k)
        tm = fmaxf(tm, p_trop[(size_t)k * PSTRIDE + base]);
    const float cs = p_cls[base];
    const float gs = p_gate[base];

    const float tv = tm + trop_b[o];
    float fmx = -1e30f, fmn = 1e30f;
#pragma unroll
    for (int p = 0; p < PDIM; ++p) {
        fmx = fmaxf(fmx, fmaf(tv, amax[o * PDIM + p], bmax[o * PDIM + p]));
        fmn = fminf(fmn, fmaf(tv, amin[o * PDIM + p], bmin[o * PDIM + p]));
    }
    const float a = sigmoidf_(alpha[o]);
    const float trop_out = a * fmx + (1.f - a) * fmn;
    const float cls_out = geluf_(cs + cls_b[o]);
    const float g = sigmoidf_(gs + gate_b[o]);
    const float val = h[base] + g * trop_out + (1.f - g) * cls_out;
    h[base] = val;

    float s = val, q = val * val;
#pragma unroll
    for (int off = 32; off > 0; off >>= 1) { s += __shfl_down(s, off); q += __shfl_down(q, off); }
    const int wid = o >> 6, lane = o & 63;
    if (lane == 0) { rbuf[wid] = s; qbuf[wid] = q; }
    __syncthreads();
    s = 0.f; q = 0.f;
#pragma unroll
    for (int w = 0; w < 12; ++w) { s += rbuf[w]; q += qbuf[w]; }
    const float mu = s * (1.f / HDIM);
    const float var = q * (1.f / HDIM) - mu * mu;
    const float rsig = rsqrtf(var + 1e-5f);
    const float ln_v = (val - mu) * rsig * lng[o] + lnb[o];

    if (!is_last) {
        hnT[(size_t)o * BDIM + b] = ln_v;
        hnB[base] = f2bf(ln_v);
    } else {
        float part = ln_v * head_w[o];
#pragma unroll
        for (int off = 32; off > 0; off >>= 1) part += __shfl_down(part, off);
        __syncthreads();
        if (lane == 0) rbuf[wid] = part;
        __syncthreads();
        if (o == 0) {
            float r = head_b[0];
#pragma unroll
            for (int w = 0; w < 12; ++w) r += rbuf[w];
            out[b] = r;
        }
    }
}

// ---------------------------------------------------------------------------
extern "C" void kernel_launch(void* const* d_in, const int* in_sizes, int n_in,
                              void* d_out, int out_size, void* d_ws, size_t ws_size,
                              hipStream_t stream)
{
    const float* x       = (const float*)d_in[0];
    const float* w_in    = (const float*)d_in[1];
    const float* b_in    = (const float*)d_in[2];
    const float* ln_g    = (const float*)d_in[3];
    const float* ln_b    = (const float*)d_in[4];
    const float* trop_w  = (const float*)d_in[5];
    const float* trop_b  = (const float*)d_in[6];
    const float* lf_amax = (const float*)d_in[7];
    const float* lf_bmax = (const float*)d_in[8];
    const float* lf_amin = (const float*)d_in[9];
    const float* lf_bmin = (const float*)d_in[10];
    const float* lf_alpha= (const float*)d_in[11];
    const float* gate_w  = (const float*)d_in[12];
    const float* gate_b  = (const float*)d_in[13];
    const float* cls_w   = (const float*)d_in[14];
    const float* cls_b   = (const float*)d_in[15];
    const float* out_g   = (const float*)d_in[16];
    const float* out_b   = (const float*)d_in[17];
    const float* head_w  = (const float*)d_in[18];
    const float* head_b  = (const float*)d_in[19];
    float* out = (float*)d_out;

    const size_t NBH = (size_t)BDIM * HDIM;    // 196608
    const size_t WSZ = (size_t)HDIM * HDIM;    // 589824
    float* ws = (float*)d_ws;
    float* h      = ws;                        // NBH
    float* hnT    = ws + NBH;                  // NBH fp32 [k][b]
    float* twT    = ws + 2 * NBH;              // L*WSZ fp32
    float* p_trop = twT + (size_t)NLAYERS * WSZ;         // KSPLIT*PSTRIDE
    float* p_cls  = p_trop + (size_t)KSPLIT * PSTRIDE;   // NBH
    float* p_gate = p_cls + NBH;                         // NBH
    unsigned short* hnB = (unsigned short*)(p_gate + NBH);          // NBH bf16
    unsigned short* wB  = hnB + NBH;                                // 2*L*WSZ bf16
    // total ~25 MB

    prep_k<<<dim3(12, 12, 14), 256, 0, stream>>>(trop_w, cls_w, gate_w, twT, wB,
                                                 x, w_in, b_in, ln_g, ln_b,
                                                 h, hnT, hnB);

    for (int l = 0; l < NLAYERS; ++l) {
        layer_mm_k<<<NBLK, 256, 0, stream>>>(
            hnT, twT + (size_t)l * WSZ,
            hnB, wB + (size_t)(2 * l) * WSZ,
            p_trop, p_cls, p_gate);

        const int is_last = (l == NLAYERS - 1);
        combine_k<<<BDIM, 768, 0, stream>>>(
            p_trop, p_cls, p_gate,
            trop_b + (size_t)l * HDIM,
            lf_amax + (size_t)l * HDIM * PDIM, lf_bmax + (size_t)l * HDIM * PDIM,
            lf_amin + (size_t)l * HDIM * PDIM, lf_bmin + (size_t)l * HDIM * PDIM,
            lf_alpha + (size_t)l * HDIM,
            gate_b + (size_t)l * HDIM, cls_b + (size_t)l * HDIM,
            h,
            is_last ? out_g : ln_g + (size_t)(l + 1) * HDIM,
            is_last ? out_b : ln_b + (size_t)(l + 1) * HDIM,
            hnT, hnB, head_w, head_b, out, is_last);
    }
}

// Round 5
// 211.428 us; speedup vs baseline: 1.0463x; 1.0463x over previous
//
#include <hip/hip_runtime.h>
#include <math.h>

#define HDIM 768
#define BDIM 256
#define INDIM 64
#define NLAYERS 4
#define PDIM 8
#define KSPLIT 16     // trop k-split: 16 slots x 48k
#define KLEN 48
#define CHK 16
#define TR 64
#define TC 64
#define NTROPBLK 768  // 48 spatial (4x12 of 64x64) x 16 slots -> exactly 3/CU
#define NCGBLK 192    // 4 m x 24 n x 2 mats
#define NBLK (NTROPBLK + NCGBLK)   // 960
#define PSTRIDE 196864  // NBH + 256 floats: de-alias 768KB stride in L2 sets

typedef short bf16x8 __attribute__((ext_vector_type(8)));
typedef float f32x4 __attribute__((ext_vector_type(4)));

__device__ __forceinline__ float sigmoidf_(float x) { return 1.f / (1.f + expf(-x)); }
__device__ __forceinline__ float geluf_(float x) { return 0.5f * x * (1.f + erff(x * 0.70710678118654752f)); }
__device__ __forceinline__ unsigned short f2bf(float f) {
    unsigned int u = __float_as_uint(f);
    u += 0x7FFFu + ((u >> 16) & 1u);          // RNE
    return (unsigned short)(u >> 16);
}

// async global->LDS, 16B/lane
__device__ __forceinline__ void gload_lds16(const float* g, float* l) {
    __builtin_amdgcn_global_load_lds((const __attribute__((address_space(1))) void*)g,
                                     (__attribute__((address_space(3))) void*)l, 16, 0, 0);
}

// ---------------------------------------------------------------------------
// Merged prep + input: grid (12,12,14).
//  z<4 : trop_w[l=z] [o][i] fp32 -> twT[l] [i][o] fp32
//  z in [4,12): zz=z-4, l=zz>>1, mat=zz&1: cls/gate [k][o] fp32 -> wB[o][k] bf16
//  z in [12,14): input GEMM h = x@w_in + b_in, LN(layer0) -> hnT/hnB, 1 row/blk
// ---------------------------------------------------------------------------
__global__ __launch_bounds__(256) void prep_k(const float* __restrict__ trop_w,
                                              const float* __restrict__ cls_w,
                                              const float* __restrict__ gate_w,
                                              float* __restrict__ twT,
                                              unsigned short* __restrict__ wB,
                                              const float* __restrict__ x,
                                              const float* __restrict__ w_in,
                                              const float* __restrict__ b_in,
                                              const float* __restrict__ lng,
                                              const float* __restrict__ lnb,
                                              float* __restrict__ h,
                                              float* __restrict__ hnT,
                                              unsigned short* __restrict__ hnB)
{
    __shared__ float tile[64][65];
    const int z = blockIdx.z;
    const int a0 = blockIdx.x * 64;
    const int b0 = blockIdx.y * 64;
    const int c = threadIdx.x & 63;
    const int r4 = threadIdx.x >> 6;

    if (z < NLAYERS) {
        const float* s = trop_w + (size_t)z * HDIM * HDIM;
        float* d = twT + (size_t)z * HDIM * HDIM;
#pragma unroll
        for (int it = 0; it < 16; ++it) {
            const int r = it * 4 + r4;
            tile[r][c] = s[(size_t)(a0 + r) * HDIM + b0 + c];
        }
        __syncthreads();
#pragma unroll
        for (int it = 0; it < 16; ++it) {
            const int r = it * 4 + r4;
            d[(size_t)(b0 + r) * HDIM + a0 + c] = tile[c][r];
        }
    } else if (z < 12) {
        const int zz = z - NLAYERS;
        const int l = zz >> 1, mat = zz & 1;
        const float* s = (mat ? gate_w : cls_w) + (size_t)l * HDIM * HDIM;
        unsigned short* d = wB + (size_t)zz * HDIM * HDIM;
#pragma unroll
        for (int it = 0; it < 16; ++it) {
            const int r = it * 4 + r4;                          // k
            tile[r][c] = s[(size_t)(b0 + r) * HDIM + a0 + c];   // c = o
        }
        __syncthreads();
#pragma unroll
        for (int it = 0; it < 16; ++it) {
            const int r = it * 4 + r4;                          // o
            d[(size_t)(a0 + r) * HDIM + b0 + c] = f2bf(tile[c][r]);
        }
    } else {
        // ---- input GEMM + LN(layer 0), one batch row per block ----
        const int idx = (z - 12) * 144 + blockIdx.y * 12 + blockIdx.x;
        if (idx >= BDIM) return;
        const int b = idx;
        const int t = threadIdx.x;
        float* xs = &tile[0][0];    // 64 floats
        float* rb = &tile[1][0];    // 8 floats (4 waves x s,q)
        if (t < INDIM) xs[t] = x[b * INDIM + t];
        __syncthreads();

        float acc0 = b_in[t], acc1 = b_in[t + 256], acc2 = b_in[t + 512];
#pragma unroll 8
        for (int i = 0; i < INDIM; ++i) {
            const float xv = xs[i];
            acc0 = fmaf(xv, w_in[(size_t)i * HDIM + t], acc0);
            acc1 = fmaf(xv, w_in[(size_t)i * HDIM + t + 256], acc1);
            acc2 = fmaf(xv, w_in[(size_t)i * HDIM + t + 512], acc2);
        }
        h[(size_t)b * HDIM + t] = acc0;
        h[(size_t)b * HDIM + t + 256] = acc1;
        h[(size_t)b * HDIM + t + 512] = acc2;

        float s = acc0 + acc1 + acc2;
        float q = acc0 * acc0 + acc1 * acc1 + acc2 * acc2;
#pragma unroll
        for (int off = 32; off > 0; off >>= 1) { s += __shfl_down(s, off); q += __shfl_down(q, off); }
        const int wid = t >> 6, lane = t & 63;
        if (lane == 0) { rb[wid] = s; rb[4 + wid] = q; }
        __syncthreads();
        s = rb[0] + rb[1] + rb[2] + rb[3];
        q = rb[4] + rb[5] + rb[6] + rb[7];
        const float mu = s * (1.f / HDIM);
        const float var = q * (1.f / HDIM) - mu * mu;
        const float rsig = rsqrtf(var + 1e-5f);

#pragma unroll
        for (int qq = 0; qq < 3; ++qq) {
            const int o = t + qq * 256;
            const float av = (qq == 0) ? acc0 : (qq == 1) ? acc1 : acc2;
            const float v = (av - mu) * rsig * lng[o] + lnb[o];
            hnT[(size_t)o * BDIM + b] = v;
            hnB[(size_t)b * HDIM + o] = f2bf(v);
        }
    }
}

// ---------------------------------------------------------------------------
// Kernel 1 (per layer, ONE dispatch): block-partitioned fusion.
//   blocks [0,768):   TROPICAL fp32 64x64 tiles, KLEN=48 (CHK=16 dbuf x3)
//   blocks [768,960): CLS+GATE bf16 MFMA tiles (one mat per block)
// 960 blocks: round-robin -> every CU gets exactly 3 trop (+ <=1 gemm):
// critical path 3x3072=9216 cyc vs round-3's 64 CUs x 3x4096=12288.
// LDS 16KB/block -> 4 co-resident.
// ---------------------------------------------------------------------------
__global__ __launch_bounds__(256, 2) void layer_mm_k(
    const float* __restrict__ hnT,        // fp32 [k][b]
    const float* __restrict__ twT,        // fp32 trop_w^T [k][o] (this layer)
    const unsigned short* __restrict__ hnB,  // bf16 [b][k]
    const unsigned short* __restrict__ wB,   // bf16 [mat][o][k] (this layer)
    float* __restrict__ p_trop, float* __restrict__ p_cls, float* __restrict__ p_gate)
{
    __shared__ float hn_s[2][CHK][TR];
    __shared__ float wt_s[2][CHK][TC];

    const int bx = blockIdx.x;
    const int tid = threadIdx.x;
    const int wave = tid >> 6, lane = tid & 63;

    if (bx < NTROPBLK) {
        // ---------------- tropical (fp32, exact) ----------------
        const int sp = bx % 48;                // 4 row-tiles x 12 col-tiles
        const int slot = bx / 48;              // 0..15
        const int row0 = (sp / 12) * TR;
        const int col0 = (sp % 12) * TC;
        const int k0 = slot * KLEN;

        const int tx = tid & 15, ty = tid >> 4;
        const int r0 = ty * 4, c0 = tx * 4;

        const int sr = lane >> 4;              // sub-row within 4-row seg
        const int sc = (lane & 15) * 4;        // 4-float col chunk

        float t_acc[4][4];
#pragma unroll
        for (int i = 0; i < 4; ++i)
#pragma unroll
            for (int j = 0; j < 4; ++j) t_acc[i][j] = -1e30f;

        // Each wave stages 4 k-rows (1KB) of hn and of wt per chunk.
        #define STAGE_T(buf, kb)                                                                   \
        {                                                                                          \
            gload_lds16(hnT + (size_t)((kb) + 4 * wave + sr) * BDIM + row0 + sc,                   \
                        &hn_s[buf][4 * wave][0]);                                                  \
            gload_lds16(twT + (size_t)((kb) + 4 * wave + sr) * HDIM + col0 + sc,                   \
                        &wt_s[buf][4 * wave][0]);                                                  \
        }

        STAGE_T(0, k0);
        __builtin_amdgcn_s_waitcnt(0);
        __syncthreads();

        for (int c = 0; c < KLEN / CHK; ++c) {
            const int buf = c & 1;
            if (c + 1 < KLEN / CHK) STAGE_T(1 - buf, k0 + (c + 1) * CHK);
#pragma unroll
            for (int k = 0; k < CHK; ++k) {
                const float4 hv = *(const float4*)&hn_s[buf][k][r0];
                const float4 wv = *(const float4*)&wt_s[buf][k][c0];
                const float hf[4] = {hv.x, hv.y, hv.z, hv.w};
                const float wf[4] = {wv.x, wv.y, wv.z, wv.w};
#pragma unroll
                for (int i = 0; i < 4; ++i)
#pragma unroll
                    for (int j = 0; j < 4; ++j)
                        t_acc[i][j] = fmaxf(t_acc[i][j], hf[i] + wf[j]);
            }
            __builtin_amdgcn_s_waitcnt(0);
            __syncthreads();
        }
        #undef STAGE_T

        const size_t base = (size_t)slot * PSTRIDE;
#pragma unroll
        for (int i = 0; i < 4; ++i) {
            const size_t off = base + (size_t)(row0 + r0 + i) * HDIM + col0 + c0;
            *(float4*)(p_trop + off) = make_float4(t_acc[i][0], t_acc[i][1], t_acc[i][2], t_acc[i][3]);
        }
    } else {
        // ---------------- cls+gate (bf16 MFMA, full K, 1 mat/block) --------
        // Layouts (HW-verified): A[m=lane&15][k=q*8+j], B[k][n=lane&15],
        // D[m=q*4+r][n=lane&15].
        const int cb = bx - NTROPBLK;          // 0..191
        const int mat = cb & 1;
        const int nt = (cb >> 1) % 24;         // 24 n-tiles of 32
        const int mt = cb / 48;                // 4 m-tiles of 64
        const int m0 = mt * 64 + wave * 16;
        const int n0 = nt * 32;
        const int lm = lane & 15, q = lane >> 4;

        const unsigned short* wmat = wB + (size_t)mat * HDIM * HDIM;
        float* pout = mat ? p_gate : p_cls;

        f32x4 acc[2];
        acc[0] = (f32x4){0.f, 0.f, 0.f, 0.f};
        acc[1] = (f32x4){0.f, 0.f, 0.f, 0.f};

        const unsigned short* aptr = hnB + (size_t)(m0 + lm) * HDIM + q * 8;
        const unsigned short* b0 = wmat + (size_t)(n0 + lm) * HDIM + q * 8;
        const unsigned short* b1 = b0 + (size_t)16 * HDIM;

#pragma unroll 4
        for (int k0 = 0; k0 < HDIM; k0 += 32) {
            const bf16x8 a  = *(const bf16x8*)(aptr + k0);
            const bf16x8 v0 = *(const bf16x8*)(b0 + k0);
            const bf16x8 v1 = *(const bf16x8*)(b1 + k0);
            acc[0] = __builtin_amdgcn_mfma_f32_16x16x32_bf16(a, v0, acc[0], 0, 0, 0);
            acc[1] = __builtin_amdgcn_mfma_f32_16x16x32_bf16(a, v1, acc[1], 0, 0, 0);
        }

#pragma unroll
        for (int nn = 0; nn < 2; ++nn)
#pragma unroll
            for (int r = 0; r < 4; ++r)
                pout[(size_t)(m0 + q * 4 + r) * HDIM + n0 + nn * 16 + lm] = acc[nn][r];
    }
}

// ---------------------------------------------------------------------------
// Kernel 2 (per layer): reduce trop partials, LF activation, gelu, gate,
// residual, then LN -> hnT/hnB for next layer (or final LN + head -> out).
// ---------------------------------------------------------------------------
__global__ __launch_bounds__(768) void combine_k(
    const float* __restrict__ p_trop, const float* __restrict__ p_cls, const float* __restrict__ p_gate,
    const float* __restrict__ trop_b,
    const float* __restrict__ amax, const float* __restrict__ bmax,
    const float* __restrict__ amin, const float* __restrict__ bmin,
    const float* __restrict__ alpha,
    const float* __restrict__ gate_b, const float* __restrict__ cls_b,
    float* __restrict__ h,
    const float* __restrict__ lng, const float* __restrict__ lnb,
    float* __restrict__ hnT, unsigned short* __restrict__ hnB,
    const float* __restrict__ head_w, const float* __restrict__ head_b,
    float* __restrict__ out, const int is_last)
{
    const int b = blockIdx.x;
    const int o = threadIdx.x;         // 0..767
    __shared__ float rbuf[12], qbuf[12];

    const size_t base = (size_t)b * HDIM + o;
    float tm = -1e30f;
#pragma unroll
    for (int k = 0; k < KSPLIT; ++k)
        tm = fmaxf(tm, p_trop[(size_t)k * PSTRIDE + base]);
    const float cs = p_cls[base];
    const float gs = p_gate[base];

    const float tv = tm + trop_b[o];
    float fmx = -1e30f, fmn = 1e30f;
#pragma unroll
    for (int p = 0; p < PDIM; ++p) {
        fmx = fmaxf(fmx, fmaf(tv, amax[o * PDIM + p], bmax[o * PDIM + p]));
        fmn = fminf(fmn, fmaf(tv, amin[o * PDIM + p], bmin[o * PDIM + p]));
    }
    const float a = sigmoidf_(alpha[o]);
    const float trop_out = a * fmx + (1.f - a) * fmn;
    const float cls_out = geluf_(cs + cls_b[o]);
    const float g = sigmoidf_(gs + gate_b[o]);
    const float val = h[base] + g * trop_out + (1.f - g) * cls_out;
    h[base] = val;

    float s = val, q = val * val;
#pragma unroll
    for (int off = 32; off > 0; off >>= 1) { s += __shfl_down(s, off); q += __shfl_down(q, off); }
    const int wid = o >> 6, lane = o & 63;
    if (lane == 0) { rbuf[wid] = s; qbuf[wid] = q; }
    __syncthreads();
    s = 0.f; q = 0.f;
#pragma unroll
    for (int w = 0; w < 12; ++w) { s += rbuf[w]; q += qbuf[w]; }
    const float mu = s * (1.f / HDIM);
    const float var = q * (1.f / HDIM) - mu * mu;
    const float rsig = rsqrtf(var + 1e-5f);
    const float ln_v = (val - mu) * rsig * lng[o] + lnb[o];

    if (!is_last) {
        hnT[(size_t)o * BDIM + b] = ln_v;
        hnB[base] = f2bf(ln_v);
    } else {
        float part = ln_v * head_w[o];
#pragma unroll
        for (int off = 32; off > 0; off >>= 1) part += __shfl_down(part, off);
        __syncthreads();
        if (lane == 0) rbuf[wid] = part;
        __syncthreads();
        if (o == 0) {
            float r = head_b[0];
#pragma unroll
            for (int w = 0; w < 12; ++w) r += rbuf[w];
            out[b] = r;
        }
    }
}

// ---------------------------------------------------------------------------
extern "C" void kernel_launch(void* const* d_in, const int* in_sizes, int n_in,
                              void* d_out, int out_size, void* d_ws, size_t ws_size,
                              hipStream_t stream)
{
    const float* x       = (const float*)d_in[0];
    const float* w_in    = (const float*)d_in[1];
    const float* b_in    = (const float*)d_in[2];
    const float* ln_g    = (const float*)d_in[3];
    const float* ln_b    = (const float*)d_in[4];
    const float* trop_w  = (const float*)d_in[5];
    const float* trop_b  = (const float*)d_in[6];
    const float* lf_amax = (const float*)d_in[7];
    const float* lf_bmax = (const float*)d_in[8];
    const float* lf_amin = (const float*)d_in[9];
    const float* lf_bmin = (const float*)d_in[10];
    const float* lf_alpha= (const float*)d_in[11];
    const float* gate_w  = (const float*)d_in[12];
    const float* gate_b  = (const float*)d_in[13];
    const float* cls_w   = (const float*)d_in[14];
    const float* cls_b   = (const float*)d_in[15];
    const float* out_g   = (const float*)d_in[16];
    const float* out_b   = (const float*)d_in[17];
    const float* head_w  = (const float*)d_in[18];
    const float* head_b  = (const float*)d_in[19];
    float* out = (float*)d_out;

    const size_t NBH = (size_t)BDIM * HDIM;    // 196608
    const size_t WSZ = (size_t)HDIM * HDIM;    // 589824
    float* ws = (float*)d_ws;
    float* h      = ws;                        // NBH
    float* hnT    = ws + NBH;                  // NBH fp32 [k][b]
    float* twT    = ws + 2 * NBH;              // L*WSZ fp32
    float* p_trop = twT + (size_t)NLAYERS * WSZ;         // KSPLIT*PSTRIDE
    float* p_cls  = p_trop + (size_t)KSPLIT * PSTRIDE;   // NBH
    float* p_gate = p_cls + NBH;                         // NBH
    unsigned short* hnB = (unsigned short*)(p_gate + NBH);          // NBH bf16
    unsigned short* wB  = hnB + NBH;                                // 2*L*WSZ bf16
    // total ~31 MB

    prep_k<<<dim3(12, 12, 14), 256, 0, stream>>>(trop_w, cls_w, gate_w, twT, wB,
                                                 x, w_in, b_in, ln_g, ln_b,
                                                 h, hnT, hnB);

    for (int l = 0; l < NLAYERS; ++l) {
        layer_mm_k<<<NBLK, 256, 0, stream>>>(
            hnT, twT + (size_t)l * WSZ,
            hnB, wB + (size_t)(2 * l) * WSZ,
            p_trop, p_cls, p_gate);

        const int is_last = (l == NLAYERS - 1);
        combine_k<<<BDIM, 768, 0, stream>>>(
            p_trop, p_cls, p_gate,
            trop_b + (size_t)l * HDIM,
            lf_amax + (size_t)l * HDIM * PDIM, lf_bmax + (size_t)l * HDIM * PDIM,
            lf_amin + (size_t)l * HDIM * PDIM, lf_bmin + (size_t)l * HDIM * PDIM,
            lf_alpha + (size_t)l * HDIM,
            gate_b + (size_t)l * HDIM, cls_b + (size_t)l * HDIM,
            h,
            is_last ? out_g : ln_g + (size_t)(l + 1) * HDIM,
            is_last ? out_b : ln_b + (size_t)(l + 1) * HDIM,
            hnT, hnB, head_w, head_b, out, is_last);
    }
}

// Round 6
// 209.411 us; speedup vs baseline: 1.0564x; 1.0096x over previous
//
#include <hip/hip_runtime.h>
#include <math.h>

#define HDIM 768
#define BDIM 256
#define INDIM 64
#define NLAYERS 4
#define PDIM 8
#define KSPLIT 16     // trop k-split: 16 slots x 48k
#define KLEN 48
#define CHK 16
#define TR 64
#define TC 64
#define NTROPBLK 768  // 48 spatial (4x12 of 64x64) x 16 slots -> exactly 3/CU
#define NCGBLK 192    // 4 m x 24 n x 2 mats
#define NBLK (NTROPBLK + NCGBLK)   // 960
#define PSTRIDE 196864  // NBH + 256 floats: de-alias 768KB stride in L2 sets

typedef short bf16x8 __attribute__((ext_vector_type(8)));
typedef float f32x4 __attribute__((ext_vector_type(4)));
typedef float f32x2 __attribute__((ext_vector_type(2)));

__device__ __forceinline__ float sigmoidf_(float x) { return 1.f / (1.f + expf(-x)); }
__device__ __forceinline__ float geluf_(float x) { return 0.5f * x * (1.f + erff(x * 0.70710678118654752f)); }
__device__ __forceinline__ unsigned short f2bf(float f) {
    unsigned int u = __float_as_uint(f);
    u += 0x7FFFu + ((u >> 16) & 1u);          // RNE
    return (unsigned short)(u >> 16);
}

// async global->LDS, 16B/lane
__device__ __forceinline__ void gload_lds16(const float* g, float* l) {
    __builtin_amdgcn_global_load_lds((const __attribute__((address_space(1))) void*)g,
                                     (__attribute__((address_space(3))) void*)l, 16, 0, 0);
}

// ---------------------------------------------------------------------------
// Merged prep + input: grid (12,12,14).
//  z<4 : trop_w[l=z] [o][i] fp32 -> twT[l] [i][o] fp32
//  z in [4,12): zz=z-4, l=zz>>1, mat=zz&1: cls/gate [k][o] fp32 -> wB[o][k] bf16
//  z in [12,14): input GEMM h = x@w_in + b_in, LN(layer0) -> hnT/hnB, 1 row/blk
// ---------------------------------------------------------------------------
__global__ __launch_bounds__(256) void prep_k(const float* __restrict__ trop_w,
                                              const float* __restrict__ cls_w,
                                              const float* __restrict__ gate_w,
                                              float* __restrict__ twT,
                                              unsigned short* __restrict__ wB,
                                              const float* __restrict__ x,
                                              const float* __restrict__ w_in,
                                              const float* __restrict__ b_in,
                                              const float* __restrict__ lng,
                                              const float* __restrict__ lnb,
                                              float* __restrict__ h,
                                              float* __restrict__ hnT,
                                              unsigned short* __restrict__ hnB)
{
    __shared__ float tile[64][65];
    const int z = blockIdx.z;
    const int a0 = blockIdx.x * 64;
    const int b0 = blockIdx.y * 64;
    const int c = threadIdx.x & 63;
    const int r4 = threadIdx.x >> 6;

    if (z < NLAYERS) {
        const float* s = trop_w + (size_t)z * HDIM * HDIM;
        float* d = twT + (size_t)z * HDIM * HDIM;
#pragma unroll
        for (int it = 0; it < 16; ++it) {
            const int r = it * 4 + r4;
            tile[r][c] = s[(size_t)(a0 + r) * HDIM + b0 + c];
        }
        __syncthreads();
#pragma unroll
        for (int it = 0; it < 16; ++it) {
            const int r = it * 4 + r4;
            d[(size_t)(b0 + r) * HDIM + a0 + c] = tile[c][r];
        }
    } else if (z < 12) {
        const int zz = z - NLAYERS;
        const int l = zz >> 1, mat = zz & 1;
        const float* s = (mat ? gate_w : cls_w) + (size_t)l * HDIM * HDIM;
        unsigned short* d = wB + (size_t)zz * HDIM * HDIM;
#pragma unroll
        for (int it = 0; it < 16; ++it) {
            const int r = it * 4 + r4;                          // k
            tile[r][c] = s[(size_t)(b0 + r) * HDIM + a0 + c];   // c = o
        }
        __syncthreads();
#pragma unroll
        for (int it = 0; it < 16; ++it) {
            const int r = it * 4 + r4;                          // o
            d[(size_t)(a0 + r) * HDIM + b0 + c] = f2bf(tile[c][r]);
        }
    } else {
        // ---- input GEMM + LN(layer 0), one batch row per block ----
        const int idx = (z - 12) * 144 + blockIdx.y * 12 + blockIdx.x;
        if (idx >= BDIM) return;
        const int b = idx;
        const int t = threadIdx.x;
        float* xs = &tile[0][0];    // 64 floats
        float* rb = &tile[1][0];    // 8 floats (4 waves x s,q)
        if (t < INDIM) xs[t] = x[b * INDIM + t];
        __syncthreads();

        float acc0 = b_in[t], acc1 = b_in[t + 256], acc2 = b_in[t + 512];
#pragma unroll 8
        for (int i = 0; i < INDIM; ++i) {
            const float xv = xs[i];
            acc0 = fmaf(xv, w_in[(size_t)i * HDIM + t], acc0);
            acc1 = fmaf(xv, w_in[(size_t)i * HDIM + t + 256], acc1);
            acc2 = fmaf(xv, w_in[(size_t)i * HDIM + t + 512], acc2);
        }
        h[(size_t)b * HDIM + t] = acc0;
        h[(size_t)b * HDIM + t + 256] = acc1;
        h[(size_t)b * HDIM + t + 512] = acc2;

        float s = acc0 + acc1 + acc2;
        float q = acc0 * acc0 + acc1 * acc1 + acc2 * acc2;
#pragma unroll
        for (int off = 32; off > 0; off >>= 1) { s += __shfl_down(s, off); q += __shfl_down(q, off); }
        const int wid = t >> 6, lane = t & 63;
        if (lane == 0) { rb[wid] = s; rb[4 + wid] = q; }
        __syncthreads();
        s = rb[0] + rb[1] + rb[2] + rb[3];
        q = rb[4] + rb[5] + rb[6] + rb[7];
        const float mu = s * (1.f / HDIM);
        const float var = q * (1.f / HDIM) - mu * mu;
        const float rsig = rsqrtf(var + 1e-5f);

#pragma unroll
        for (int qq = 0; qq < 3; ++qq) {
            const int o = t + qq * 256;
            const float av = (qq == 0) ? acc0 : (qq == 1) ? acc1 : acc2;
            const float v = (av - mu) * rsig * lng[o] + lnb[o];
            hnT[(size_t)o * BDIM + b] = v;
            hnB[(size_t)b * HDIM + o] = f2bf(v);
        }
    }
}

// ---------------------------------------------------------------------------
// Kernel 1 (per layer, ONE dispatch): block-partitioned fusion.
//   blocks [0,768):   TROPICAL fp32 64x64 tiles, KLEN=48 (CHK=16 dbuf x3)
//   blocks [768,960): CLS+GATE bf16 MFMA tiles (one mat per block)
// Trop inner loop: k processed in PAIRS -> v_pk_add_f32 (j-dim packed adds,
// operand pairs are consecutive VGPRs from the float4 loads) + v_max3_f32
// (acc,s_k,s_k1 fusion).  32 VALU instr per 2k per thread vs 64 scalar.
// ---------------------------------------------------------------------------
__global__ __launch_bounds__(256, 2) void layer_mm_k(
    const float* __restrict__ hnT,        // fp32 [k][b]
    const float* __restrict__ twT,        // fp32 trop_w^T [k][o] (this layer)
    const unsigned short* __restrict__ hnB,  // bf16 [b][k]
    const unsigned short* __restrict__ wB,   // bf16 [mat][o][k] (this layer)
    float* __restrict__ p_trop, float* __restrict__ p_cls, float* __restrict__ p_gate)
{
    __shared__ float hn_s[2][CHK][TR];
    __shared__ float wt_s[2][CHK][TC];

    const int bx = blockIdx.x;
    const int tid = threadIdx.x;
    const int wave = tid >> 6, lane = tid & 63;

    if (bx < NTROPBLK) {
        // ---------------- tropical (fp32, exact) ----------------
        const int sp = bx % 48;                // 4 row-tiles x 12 col-tiles
        const int slot = bx / 48;              // 0..15
        const int row0 = (sp / 12) * TR;
        const int col0 = (sp % 12) * TC;
        const int k0 = slot * KLEN;

        const int tx = tid & 15, ty = tid >> 4;
        const int r0 = ty * 4, c0 = tx * 4;

        const int sr = lane >> 4;              // sub-row within 4-row seg
        const int sc = (lane & 15) * 4;        // 4-float col chunk

        float t_acc[4][4];
#pragma unroll
        for (int i = 0; i < 4; ++i)
#pragma unroll
            for (int j = 0; j < 4; ++j) t_acc[i][j] = -1e30f;

        // Each wave stages 4 k-rows (1KB) of hn and of wt per chunk.
        #define STAGE_T(buf, kb)                                                                   \
        {                                                                                          \
            gload_lds16(hnT + (size_t)((kb) + 4 * wave + sr) * BDIM + row0 + sc,                   \
                        &hn_s[buf][4 * wave][0]);                                                  \
            gload_lds16(twT + (size_t)((kb) + 4 * wave + sr) * HDIM + col0 + sc,                   \
                        &wt_s[buf][4 * wave][0]);                                                  \
        }

        STAGE_T(0, k0);
        __builtin_amdgcn_s_waitcnt(0);
        __syncthreads();

        for (int c = 0; c < KLEN / CHK; ++c) {
            const int buf = c & 1;
            if (c + 1 < KLEN / CHK) STAGE_T(1 - buf, k0 + (c + 1) * CHK);
#pragma unroll
            for (int k = 0; k < CHK; k += 2) {
                const float4 h0 = *(const float4*)&hn_s[buf][k][r0];
                const float4 w0 = *(const float4*)&wt_s[buf][k][c0];
                const float4 h1 = *(const float4*)&hn_s[buf][k + 1][r0];
                const float4 w1 = *(const float4*)&wt_s[buf][k + 1][c0];
                const f32x2 w0lo = {w0.x, w0.y}, w0hi = {w0.z, w0.w};
                const f32x2 w1lo = {w1.x, w1.y}, w1hi = {w1.z, w1.w};
                const float hf0[4] = {h0.x, h0.y, h0.z, h0.w};
                const float hf1[4] = {h1.x, h1.y, h1.z, h1.w};
#pragma unroll
                for (int i = 0; i < 4; ++i) {
                    const f32x2 a0 = {hf0[i], hf0[i]};
                    const f32x2 a1 = {hf1[i], hf1[i]};
                    const f32x2 s01 = w0lo + a0;   // v_pk_add_f32
                    const f32x2 s23 = w0hi + a0;
                    const f32x2 t01 = w1lo + a1;
                    const f32x2 t23 = w1hi + a1;
                    t_acc[i][0] = fmaxf(fmaxf(t_acc[i][0], s01.x), t01.x);  // v_max3_f32
                    t_acc[i][1] = fmaxf(fmaxf(t_acc[i][1], s01.y), t01.y);
                    t_acc[i][2] = fmaxf(fmaxf(t_acc[i][2], s23.x), t23.x);
                    t_acc[i][3] = fmaxf(fmaxf(t_acc[i][3], s23.y), t23.y);
                }
            }
            __builtin_amdgcn_s_waitcnt(0);
            __syncthreads();
        }
        #undef STAGE_T

        const size_t base = (size_t)slot * PSTRIDE;
#pragma unroll
        for (int i = 0; i < 4; ++i) {
            const size_t off = base + (size_t)(row0 + r0 + i) * HDIM + col0 + c0;
            *(float4*)(p_trop + off) = make_float4(t_acc[i][0], t_acc[i][1], t_acc[i][2], t_acc[i][3]);
        }
    } else {
        // ---------------- cls+gate (bf16 MFMA, full K, 1 mat/block) --------
        // Layouts (HW-verified): A[m=lane&15][k=q*8+j], B[k][n=lane&15],
        // D[m=q*4+r][n=lane&15].
        const int cb = bx - NTROPBLK;          // 0..191
        const int mat = cb & 1;
        const int nt = (cb >> 1) % 24;         // 24 n-tiles of 32
        const int mt = cb / 48;                // 4 m-tiles of 64
        const int m0 = mt * 64 + wave * 16;
        const int n0 = nt * 32;
        const int lm = lane & 15, q = lane >> 4;

        const unsigned short* wmat = wB + (size_t)mat * HDIM * HDIM;
        float* pout = mat ? p_gate : p_cls;

        f32x4 acc[2];
        acc[0] = (f32x4){0.f, 0.f, 0.f, 0.f};
        acc[1] = (f32x4){0.f, 0.f, 0.f, 0.f};

        const unsigned short* aptr = hnB + (size_t)(m0 + lm) * HDIM + q * 8;
        const unsigned short* b0 = wmat + (size_t)(n0 + lm) * HDIM + q * 8;
        const unsigned short* b1 = b0 + (size_t)16 * HDIM;

#pragma unroll 4
        for (int k0 = 0; k0 < HDIM; k0 += 32) {
            const bf16x8 a  = *(const bf16x8*)(aptr + k0);
            const bf16x8 v0 = *(const bf16x8*)(b0 + k0);
            const bf16x8 v1 = *(const bf16x8*)(b1 + k0);
            acc[0] = __builtin_amdgcn_mfma_f32_16x16x32_bf16(a, v0, acc[0], 0, 0, 0);
            acc[1] = __builtin_amdgcn_mfma_f32_16x16x32_bf16(a, v1, acc[1], 0, 0, 0);
        }

#pragma unroll
        for (int nn = 0; nn < 2; ++nn)
#pragma unroll
            for (int r = 0; r < 4; ++r)
                pout[(size_t)(m0 + q * 4 + r) * HDIM + n0 + nn * 16 + lm] = acc[nn][r];
    }
}

// ---------------------------------------------------------------------------
// Kernel 2 (per layer): reduce trop partials, LF activation, gelu, gate,
// residual, then LN -> hnT/hnB for next layer (or final LN + head -> out).
// ---------------------------------------------------------------------------
__global__ __launch_bounds__(768) void combine_k(
    const float* __restrict__ p_trop, const float* __restrict__ p_cls, const float* __restrict__ p_gate,
    const float* __restrict__ trop_b,
    const float* __restrict__ amax, const float* __restrict__ bmax,
    const float* __restrict__ amin, const float* __restrict__ bmin,
    const float* __restrict__ alpha,
    const float* __restrict__ gate_b, const float* __restrict__ cls_b,
    float* __restrict__ h,
    const float* __restrict__ lng, const float* __restrict__ lnb,
    float* __restrict__ hnT, unsigned short* __restrict__ hnB,
    const float* __restrict__ head_w, const float* __restrict__ head_b,
    float* __restrict__ out, const int is_last)
{
    const int b = blockIdx.x;
    const int o = threadIdx.x;         // 0..767
    __shared__ float rbuf[12], qbuf[12];

    const size_t base = (size_t)b * HDIM + o;
    float tm = -1e30f;
#pragma unroll
    for (int k = 0; k < KSPLIT; ++k)
        tm = fmaxf(tm, p_trop[(size_t)k * PSTRIDE + base]);
    const float cs = p_cls[base];
    const float gs = p_gate[base];

    const float tv = tm + trop_b[o];
    float fmx = -1e30f, fmn = 1e30f;
#pragma unroll
    for (int p = 0; p < PDIM; ++p) {
        fmx = fmaxf(fmx, fmaf(tv, amax[o * PDIM + p], bmax[o * PDIM + p]));
        fmn = fminf(fmn, fmaf(tv, amin[o * PDIM + p], bmin[o * PDIM + p]));
    }
    const float a = sigmoidf_(alpha[o]);
    const float trop_out = a * fmx + (1.f - a) * fmn;
    const float cls_out = geluf_(cs + cls_b[o]);
    const float g = sigmoidf_(gs + gate_b[o]);
    const float val = h[base] + g * trop_out + (1.f - g) * cls_out;
    h[base] = val;

    float s = val, q = val * val;
#pragma unroll
    for (int off = 32; off > 0; off >>= 1) { s += __shfl_down(s, off); q += __shfl_down(q, off); }
    const int wid = o >> 6, lane = o & 63;
    if (lane == 0) { rbuf[wid] = s; qbuf[wid] = q; }
    __syncthreads();
    s = 0.f; q = 0.f;
#pragma unroll
    for (int w = 0; w < 12; ++w) { s += rbuf[w]; q += qbuf[w]; }
    const float mu = s * (1.f / HDIM);
    const float var = q * (1.f / HDIM) - mu * mu;
    const float rsig = rsqrtf(var + 1e-5f);
    const float ln_v = (val - mu) * rsig * lng[o] + lnb[o];

    if (!is_last) {
        hnT[(size_t)o * BDIM + b] = ln_v;
        hnB[base] = f2bf(ln_v);
    } else {
        float part = ln_v * head_w[o];
#pragma unroll
        for (int off = 32; off > 0; off >>= 1) part += __shfl_down(part, off);
        __syncthreads();
        if (lane == 0) rbuf[wid] = part;
        __syncthreads();
        if (o == 0) {
            float r = head_b[0];
#pragma unroll
            for (int w = 0; w < 12; ++w) r += rbuf[w];
            out[b] = r;
        }
    }
}

// ---------------------------------------------------------------------------
extern "C" void kernel_launch(void* const* d_in, const int* in_sizes, int n_in,
                              void* d_out, int out_size, void* d_ws, size_t ws_size,
                              hipStream_t stream)
{
    const float* x       = (const float*)d_in[0];
    const float* w_in    = (const float*)d_in[1];
    const float* b_in    = (const float*)d_in[2];
    const float* ln_g    = (const float*)d_in[3];
    const float* ln_b    = (const float*)d_in[4];
    const float* trop_w  = (const float*)d_in[5];
    const float* trop_b  = (const float*)d_in[6];
    const float* lf_amax = (const float*)d_in[7];
    const float* lf_bmax = (const float*)d_in[8];
    const float* lf_amin = (const float*)d_in[9];
    const float* lf_bmin = (const float*)d_in[10];
    const float* lf_alpha= (const float*)d_in[11];
    const float* gate_w  = (const float*)d_in[12];
    const float* gate_b  = (const float*)d_in[13];
    const float* cls_w   = (const float*)d_in[14];
    const float* cls_b   = (const float*)d_in[15];
    const float* out_g   = (const float*)d_in[16];
    const float* out_b   = (const float*)d_in[17];
    const float* head_w  = (const float*)d_in[18];
    const float* head_b  = (const float*)d_in[19];
    float* out = (float*)d_out;

    const size_t NBH = (size_t)BDIM * HDIM;    // 196608
    const size_t WSZ = (size_t)HDIM * HDIM;    // 589824
    float* ws = (float*)d_ws;
    float* h      = ws;                        // NBH
    float* hnT    = ws + NBH;                  // NBH fp32 [k][b]
    float* twT    = ws + 2 * NBH;              // L*WSZ fp32
    float* p_trop = twT + (size_t)NLAYERS * WSZ;         // KSPLIT*PSTRIDE
    float* p_cls  = p_trop + (size_t)KSPLIT * PSTRIDE;   // NBH
    float* p_gate = p_cls + NBH;                         // NBH
    unsigned short* hnB = (unsigned short*)(p_gate + NBH);          // NBH bf16
    unsigned short* wB  = hnB + NBH;                                // 2*L*WSZ bf16
    // total ~31 MB

    prep_k<<<dim3(12, 12, 14), 256, 0, stream>>>(trop_w, cls_w, gate_w, twT, wB,
                                                 x, w_in, b_in, ln_g, ln_b,
                                                 h, hnT, hnB);

    for (int l = 0; l < NLAYERS; ++l) {
        layer_mm_k<<<NBLK, 256, 0, stream>>>(
            hnT, twT + (size_t)l * WSZ,
            hnB, wB + (size_t)(2 * l) * WSZ,
            p_trop, p_cls, p_gate);

        const int is_last = (l == NLAYERS - 1);
        combine_k<<<BDIM, 768, 0, stream>>>(
            p_trop, p_cls, p_gate,
            trop_b + (size_t)l * HDIM,
            lf_amax + (size_t)l * HDIM * PDIM, lf_bmax + (size_t)l * HDIM * PDIM,
            lf_amin + (size_t)l * HDIM * PDIM, lf_bmin + (size_t)l * HDIM * PDIM,
            lf_alpha + (size_t)l * HDIM,
            gate_b + (size_t)l * HDIM, cls_b + (size_t)l * HDIM,
            h,
            is_last ? out_g : ln_g + (size_t)(l + 1) * HDIM,
            is_last ? out_b : ln_b + (size_t)(l + 1) * HDIM,
            hnT, hnB, head_w, head_b, out, is_last);
    }
}